// Round 5
// baseline (642.245 us; speedup 1.0000x reference)
//
#include <hip/hip_runtime.h>
#include <hip/hip_bf16.h>

#define N_NODES 50000
#define N_EDGES 600000
#define N_GRAPHS 100
#define M_PAD 50176  // 392 * 128

typedef __bf16 bf16_t;
typedef __attribute__((ext_vector_type(8))) __bf16 bf16x8;
typedef __attribute__((ext_vector_type(2))) __bf16 bf16x2;
typedef __attribute__((ext_vector_type(4))) float f32x4;

// ---------------- degree / norm ----------------
__global__ void degk(const int* __restrict__ dst, int* __restrict__ deg, int n) {
    int i = blockIdx.x * 256 + threadIdx.x;
    if (i < n) atomicAdd(&deg[dst[i]], 1);
}

__global__ void normk(const int* __restrict__ deg, float* __restrict__ norm, int n) {
    int i = blockIdx.x * 256 + threadIdx.x;
    if (i < n) {
        float d = fmaxf((float)deg[i], 1.0f);
        norm[i] = 1.0f / sqrtf(d);
    }
}

// ---------------- hierarchical exclusive scan (row offsets) ----------------
__global__ __launch_bounds__(1024) void scan1(const int* __restrict__ deg,
                                              int* __restrict__ row_off,
                                              int* __restrict__ partial, int n) {
    __shared__ int buf[1024];
    int i = blockIdx.x * 1024 + threadIdx.x;
    int v = (i < n) ? deg[i] : 0;
    buf[threadIdx.x] = v;
    __syncthreads();
    for (int off = 1; off < 1024; off <<= 1) {
        int t = (threadIdx.x >= off) ? buf[threadIdx.x - off] : 0;
        __syncthreads();
        buf[threadIdx.x] += t;
        __syncthreads();
    }
    if (i < n) row_off[i + 1] = buf[threadIdx.x];
    if (threadIdx.x == 1023) partial[blockIdx.x] = buf[1023];
}

__global__ void scan2(int* __restrict__ partial, int nchunks) {
    int lane = threadIdx.x;
    int v = (lane < nchunks) ? partial[lane] : 0;
    for (int off = 1; off < 64; off <<= 1) {
        int t = __shfl_up(v, off, 64);
        if (lane >= off) v += t;
    }
    int ex = __shfl_up(v, 1, 64);
    if (lane == 0) ex = 0;
    if (lane < nchunks) partial[lane] = ex;
}

__global__ void scan3(int* __restrict__ row_off, const int* __restrict__ partial, int n) {
    int i = blockIdx.x * 256 + threadIdx.x;
    if (i == 0) row_off[0] = 0;
    if (i < n) row_off[i + 1] += partial[i >> 10];
}

// ---------------- CSR scatter ----------------
__global__ void scatterk(const int* __restrict__ src, const int* __restrict__ dst,
                         const int* __restrict__ row_off, int* __restrict__ cursor,
                         int* __restrict__ csr_src, int n) {
    int e = blockIdx.x * 256 + threadIdx.x;
    if (e >= n) return;
    int d = dst[e];
    int pos = atomicAdd(&cursor[d], 1);
    csr_src[row_off[d] + pos] = src[e];
}

// ---------------- counting sort of nodes by degree (128 buckets) ----------------
__global__ void histk(const int* __restrict__ deg, int* __restrict__ hist, int n) {
    int i = blockIdx.x * 256 + threadIdx.x;
    if (i < n) atomicAdd(&hist[min(deg[i], 127)], 1);
}

__global__ void hscan(const int* __restrict__ hist, int* __restrict__ boff) {
    __shared__ int b[128];
    int t = threadIdx.x;  // 128 threads
    b[t] = hist[t];
    __syncthreads();
    if (t == 0) {
        int s = 0;
        for (int i = 0; i < 128; i++) { int v = b[i]; b[i] = s; s += v; }
    }
    __syncthreads();
    boff[t] = b[t];
}

__global__ void permk(const int* __restrict__ deg, const int* __restrict__ boff,
                      int* __restrict__ cur, int* __restrict__ perm, int n) {
    int i = blockIdx.x * 256 + threadIdx.x;
    if (i >= n) return;
    int b = min(deg[i], 127);
    int p = atomicAdd(&cur[b], 1);
    perm[boff[b] + p] = i;
}

// ---------------- prescale: xb = bf16(x), xs = bf16(x*norm) ----------------
__global__ void prescale(const float* __restrict__ x, const float* __restrict__ norm,
                         bf16_t* __restrict__ xb, bf16_t* __restrict__ xs, int n) {
    int i = blockIdx.x * 256 + threadIdx.x;
    if (i >= n * 64) return;
    int node = i >> 6;
    int c = (i & 63) * 2;
    float2 v = *(const float2*)(x + (size_t)node * 128 + c);
    float nd = norm[node];
    bf16x2 vb; vb[0] = (bf16_t)v.x; vb[1] = (bf16_t)v.y;
    bf16x2 vs; vs[0] = (bf16_t)(v.x * nd); vs[1] = (bf16_t)(v.y * nd);
    *(bf16x2*)(xb + (size_t)node * 128 + c) = vb;
    *(bf16x2*)(xs + (size_t)node * 128 + c) = vs;
}

// ---------------- W permute to MFMA B-fragment layout + bf16 ----------------
__global__ void permW(const float* __restrict__ W, bf16_t* __restrict__ Wp, int K, int N) {
    int i = blockIdx.x * 256 + threadIdx.x;
    if (i >= K * N) return;
    int k = i / N, n = i - k * N;
    int kt = k >> 5, q = (k >> 3) & 3, j = k & 7;
    int nt = n >> 4, ln = n & 15;
    int lane = q * 16 + ln;
    Wp[(((size_t)kt * (N >> 4) + nt) * 64 + lane) * 8 + j] = (bf16_t)W[i];
}

// ---------------- SpMM: degree-sorted, 2 nodes per 16-lane subgroup ----------------
// perm gives degree-sorted node order -> all subgroups in a wave run near-equal
// iteration counts (no divergence waste); 8 gathers in flight per wave.
template <bool SCALED>
__global__ __launch_bounds__(256) void spmm_bf16(const bf16_t* __restrict__ in,
                                                 bf16_t* __restrict__ out_c,
                                                 bf16_t* __restrict__ out_s,
                                                 const float* __restrict__ norm,
                                                 const int* __restrict__ row_off,
                                                 const int* __restrict__ csr_src,
                                                 const int* __restrict__ perm, int n) {
    int tid = threadIdx.x;
    int sub = tid >> 4;   // 16 subgroups
    int l   = tid & 15;   // feats [l*8, l*8+8)
    int base = blockIdx.x * 32 + sub * 2;
    if (base >= n) return;
    int nodeA = perm[base];
    bool hasB = (base + 1 < n);
    int nodeB = hasB ? perm[base + 1] : nodeA;

    int a0 = row_off[nodeA], a1 = row_off[nodeA + 1];
    int b0 = row_off[nodeB], b1 = row_off[nodeB + 1];
    const bf16_t* col = in + l * 8;
    float accA[8] = {}, accB[8] = {};

    int da = a1 - a0, db = b1 - b0;
    int c4 = (da < db ? da : db) & ~3;  // joint x4 portion (sorted -> da ~= db)
    int ea = a0, eb = b0;
    for (int k = 0; k < c4; k += 4) {
        int sA0 = csr_src[ea + 0], sA1 = csr_src[ea + 1], sA2 = csr_src[ea + 2], sA3 = csr_src[ea + 3];
        int sB0 = csr_src[eb + 0], sB1 = csr_src[eb + 1], sB2 = csr_src[eb + 2], sB3 = csr_src[eb + 3];
        bf16x8 vA0 = *(const bf16x8*)(col + (size_t)sA0 * 128);
        bf16x8 vA1 = *(const bf16x8*)(col + (size_t)sA1 * 128);
        bf16x8 vA2 = *(const bf16x8*)(col + (size_t)sA2 * 128);
        bf16x8 vA3 = *(const bf16x8*)(col + (size_t)sA3 * 128);
        bf16x8 vB0 = *(const bf16x8*)(col + (size_t)sB0 * 128);
        bf16x8 vB1 = *(const bf16x8*)(col + (size_t)sB1 * 128);
        bf16x8 vB2 = *(const bf16x8*)(col + (size_t)sB2 * 128);
        bf16x8 vB3 = *(const bf16x8*)(col + (size_t)sB3 * 128);
#pragma unroll
        for (int j = 0; j < 8; j++) {
            accA[j] += ((float)vA0[j] + (float)vA1[j]) + ((float)vA2[j] + (float)vA3[j]);
            accB[j] += ((float)vB0[j] + (float)vB1[j]) + ((float)vB2[j] + (float)vB3[j]);
        }
        ea += 4; eb += 4;
    }
    // A remainder
    for (; ea + 4 <= a1; ea += 4) {
        int s0 = csr_src[ea + 0], s1 = csr_src[ea + 1], s2 = csr_src[ea + 2], s3 = csr_src[ea + 3];
        bf16x8 v0 = *(const bf16x8*)(col + (size_t)s0 * 128);
        bf16x8 v1 = *(const bf16x8*)(col + (size_t)s1 * 128);
        bf16x8 v2 = *(const bf16x8*)(col + (size_t)s2 * 128);
        bf16x8 v3 = *(const bf16x8*)(col + (size_t)s3 * 128);
#pragma unroll
        for (int j = 0; j < 8; j++)
            accA[j] += ((float)v0[j] + (float)v1[j]) + ((float)v2[j] + (float)v3[j]);
    }
    for (; ea < a1; ea++) {
        int s = csr_src[ea];
        bf16x8 v = *(const bf16x8*)(col + (size_t)s * 128);
#pragma unroll
        for (int j = 0; j < 8; j++) accA[j] += (float)v[j];
    }
    // B remainder
    for (; eb + 4 <= b1; eb += 4) {
        int s0 = csr_src[eb + 0], s1 = csr_src[eb + 1], s2 = csr_src[eb + 2], s3 = csr_src[eb + 3];
        bf16x8 v0 = *(const bf16x8*)(col + (size_t)s0 * 128);
        bf16x8 v1 = *(const bf16x8*)(col + (size_t)s1 * 128);
        bf16x8 v2 = *(const bf16x8*)(col + (size_t)s2 * 128);
        bf16x8 v3 = *(const bf16x8*)(col + (size_t)s3 * 128);
#pragma unroll
        for (int j = 0; j < 8; j++)
            accB[j] += ((float)v0[j] + (float)v1[j]) + ((float)v2[j] + (float)v3[j]);
    }
    for (; eb < b1; eb++) {
        int s = csr_src[eb];
        bf16x8 v = *(const bf16x8*)(col + (size_t)s * 128);
#pragma unroll
        for (int j = 0; j < 8; j++) accB[j] += (float)v[j];
    }

    float ndA = norm[nodeA], ndB = norm[nodeB];
    bf16x8 ocA, osA, ocB, osB;
#pragma unroll
    for (int j = 0; j < 8; j++) {
        float cA = accA[j] * ndA;
        ocA[j] = (bf16_t)cA; osA[j] = (bf16_t)(cA * ndA);
        float cB = accB[j] * ndB;
        ocB[j] = (bf16_t)cB; osB[j] = (bf16_t)(cB * ndB);
    }
    *(bf16x8*)(out_c + (size_t)nodeA * 128 + l * 8) = ocA;
    if (SCALED) *(bf16x8*)(out_s + (size_t)nodeA * 128 + l * 8) = osA;
    if (hasB) {
        *(bf16x8*)(out_c + (size_t)nodeB * 128 + l * 8) = ocB;
        if (SCALED) *(bf16x8*)(out_s + (size_t)nodeB * 128 + l * 8) = osB;
    }
}

// ---------------- MFMA concat-GEMM: out = relu([f0|f1|f2] @ W + b) ----------------
template <int NT, bool LAYER1>
__global__ __launch_bounds__(256) void gemm_mfma(const bf16_t* __restrict__ f0,
                                                 const bf16_t* __restrict__ f1,
                                                 const bf16_t* __restrict__ f2,
                                                 const bf16_t* __restrict__ Wp,
                                                 const float* __restrict__ bias,
                                                 const float* __restrict__ norm,
                                                 bf16_t* __restrict__ out_b,
                                                 bf16_t* __restrict__ out_s,
                                                 float* __restrict__ out_f, int M) {
    int wave = threadIdx.x >> 6;
    int lane = threadIdx.x & 63;
    int q = lane >> 4, ln = lane & 15;
    int row0 = blockIdx.x * 128 + wave * 32;

    f32x4 acc[2][NT] = {};
    const bf16_t* feats[3] = {f0, f1, f2};
    const bf16x8* Wf = (const bf16x8*)Wp;

#pragma unroll
    for (int kc = 0; kc < 12; kc++) {
        const bf16_t* A = feats[kc >> 2] + (size_t)(kc & 3) * 32 + q * 8;
        bf16x8 a0 = *(const bf16x8*)(A + (size_t)(row0 + ln) * 128);
        bf16x8 a1 = *(const bf16x8*)(A + (size_t)(row0 + 16 + ln) * 128);
        const bf16x8* Bp = Wf + (size_t)kc * NT * 64 + lane;
#pragma unroll
        for (int nt = 0; nt < NT; nt++) {
            bf16x8 b = Bp[nt * 64];
            acc[0][nt] = __builtin_amdgcn_mfma_f32_16x16x32_bf16(a0, b, acc[0][nt], 0, 0, 0);
            acc[1][nt] = __builtin_amdgcn_mfma_f32_16x16x32_bf16(a1, b, acc[1][nt], 0, 0, 0);
        }
    }

    float bv[NT];
#pragma unroll
    for (int nt = 0; nt < NT; nt++) bv[nt] = bias[nt * 16 + ln];

#pragma unroll
    for (int mt = 0; mt < 2; mt++) {
#pragma unroll
        for (int r = 0; r < 4; r++) {
            int row = row0 + mt * 16 + q * 4 + r;
            if (row >= M) continue;
            float nd = LAYER1 ? norm[row] : 0.f;
#pragma unroll
            for (int nt = 0; nt < NT; nt++) {
                int col = nt * 16 + ln;
                float val = fmaxf(acc[mt][nt][r] + bv[nt], 0.f);
                if (LAYER1) {
                    out_b[(size_t)row * 128 + col] = (bf16_t)val;
                    out_s[(size_t)row * 128 + col] = (bf16_t)(val * nd);
                } else {
                    out_f[(size_t)row * 64 + col] = val;
                }
            }
        }
    }
}

// ---------------- parallel per-graph max pool ----------------
__global__ __launch_bounds__(256) void maxpool2(const float* __restrict__ hF,
                                                const int* __restrict__ gid,
                                                unsigned int* __restrict__ out, int n) {
    int wave = threadIdx.x >> 6;
    int lane = threadIdx.x & 63;
    int n0 = blockIdx.x * 256 + wave * 64;
    if (n0 >= n) return;
    int n1 = min(n0 + 64, n);
    int cur = gid[n0];
    float m = 0.f;
    int i = n0;
    for (; i + 4 <= n1; i += 4) {
        int g0 = gid[i + 0], g1 = gid[i + 1], g2 = gid[i + 2], g3 = gid[i + 3];
        float v0 = hF[(size_t)(i + 0) * 64 + lane];
        float v1 = hF[(size_t)(i + 1) * 64 + lane];
        float v2 = hF[(size_t)(i + 2) * 64 + lane];
        float v3 = hF[(size_t)(i + 3) * 64 + lane];
        if (g0 != cur) { atomicMax(&out[cur * 64 + lane], __float_as_uint(m)); cur = g0; m = v0; } else m = fmaxf(m, v0);
        if (g1 != cur) { atomicMax(&out[cur * 64 + lane], __float_as_uint(m)); cur = g1; m = v1; } else m = fmaxf(m, v1);
        if (g2 != cur) { atomicMax(&out[cur * 64 + lane], __float_as_uint(m)); cur = g2; m = v2; } else m = fmaxf(m, v2);
        if (g3 != cur) { atomicMax(&out[cur * 64 + lane], __float_as_uint(m)); cur = g3; m = v3; } else m = fmaxf(m, v3);
    }
    for (; i < n1; i++) {
        int g = gid[i];
        float v = hF[(size_t)i * 64 + lane];
        if (g != cur) { atomicMax(&out[cur * 64 + lane], __float_as_uint(m)); cur = g; m = v; }
        else m = fmaxf(m, v);
    }
    atomicMax(&out[cur * 64 + lane], __float_as_uint(m));
}

extern "C" void kernel_launch(void* const* d_in, const int* in_sizes, int n_in,
                              void* d_out, int out_size, void* d_ws, size_t ws_size,
                              hipStream_t stream) {
    const float* x  = (const float*)d_in[0];
    const float* W1 = (const float*)d_in[1];
    const float* b1 = (const float*)d_in[2];
    const float* W2 = (const float*)d_in[3];
    const float* b2 = (const float*)d_in[4];
    const int* src  = (const int*)d_in[5];
    const int* dst  = (const int*)d_in[6];
    const int* gid  = (const int*)d_in[7];
    float* out = (float*)d_out;

    char* ws = (char*)d_ws;
    size_t off = 0;
    auto take = [&](size_t bytes) {
        void* p = ws + off;
        off = (off + bytes + 255) & ~(size_t)255;
        return p;
    };
    int* deg     = (int*)take((size_t)N_NODES * 4);
    int* cursor  = (int*)take((size_t)N_NODES * 4);
    int* hist    = (int*)take(128 * 4);
    int* hcur    = (int*)take(128 * 4);
    size_t zero_bytes = off;
    float* norm  = (float*)take((size_t)N_NODES * 4);
    int* row_off = (int*)take((size_t)(N_NODES + 1) * 4);
    int* partial = (int*)take(64 * 4);
    int* boff    = (int*)take(128 * 4);
    int* perm    = (int*)take((size_t)N_NODES * 4);
    int* csr_src = (int*)take((size_t)N_EDGES * 4);
    bf16_t* Wp1  = (bf16_t*)take((size_t)384 * 128 * 2);
    bf16_t* Wp2  = (bf16_t*)take((size_t)384 * 64 * 2);
    bf16_t* B0 = (bf16_t*)take((size_t)M_PAD * 128 * 2);  // xb      -> hF (fp32 64c)
    bf16_t* B1 = (bf16_t*)take((size_t)M_PAD * 128 * 2);  // xs      -> hL1s
    bf16_t* B2 = (bf16_t*)take((size_t)M_PAD * 128 * 2);  // c1b     -> d1b
    bf16_t* B3 = (bf16_t*)take((size_t)M_PAD * 128 * 2);  // c2b     -> d2b
    bf16_t* B4 = (bf16_t*)take((size_t)M_PAD * 128 * 2);  // u1b     -> u2b
    bf16_t* B5 = (bf16_t*)take((size_t)M_PAD * 128 * 2);  // hL1b
    (void)ws_size; (void)in_sizes; (void)n_in; (void)out_size;

    hipMemsetAsync(d_ws, 0, zero_bytes, stream);
    hipMemsetAsync(d_out, 0, (size_t)N_GRAPHS * 64 * 4, stream);

    degk<<<(N_EDGES + 255) / 256, 256, 0, stream>>>(dst, deg, N_EDGES);
    normk<<<(N_NODES + 255) / 256, 256, 0, stream>>>(deg, norm, N_NODES);

    int nchunks = (N_NODES + 1023) / 1024;
    scan1<<<nchunks, 1024, 0, stream>>>(deg, row_off, partial, N_NODES);
    scan2<<<1, 64, 0, stream>>>(partial, nchunks);
    scan3<<<(N_NODES + 255) / 256, 256, 0, stream>>>(row_off, partial, N_NODES);
    scatterk<<<(N_EDGES + 255) / 256, 256, 0, stream>>>(src, dst, row_off, cursor, csr_src, N_EDGES);

    // degree sort
    histk<<<(N_NODES + 255) / 256, 256, 0, stream>>>(deg, hist, N_NODES);
    hscan<<<1, 128, 0, stream>>>(hist, boff);
    permk<<<(N_NODES + 255) / 256, 256, 0, stream>>>(deg, boff, hcur, perm, N_NODES);

    prescale<<<(N_NODES * 64 + 255) / 256, 256, 0, stream>>>(x, norm, B0, B1, N_NODES);
    permW<<<(384 * 128 + 255) / 256, 256, 0, stream>>>(W1, Wp1, 384, 128);
    permW<<<(384 * 64 + 255) / 256, 256, 0, stream>>>(W2, Wp2, 384, 64);

    int spmm_grid = (N_NODES + 31) / 32;  // 32 nodes per block
    int gemm_grid = M_PAD / 128;          // 392
    // layer 1: hops
    spmm_bf16<true><<<spmm_grid, 256, 0, stream>>>(B1, B2, B4, norm, row_off, csr_src, perm, N_NODES);
    spmm_bf16<false><<<spmm_grid, 256, 0, stream>>>(B4, B3, nullptr, norm, row_off, csr_src, perm, N_NODES);
    // layer 1: GEMM -> hL1b (B5), hL1s (B1)
    gemm_mfma<8, true><<<gemm_grid, 256, 0, stream>>>(B0, B2, B3, Wp1, b1, norm, B5, B1, nullptr, N_NODES);
    // layer 2: hops
    spmm_bf16<true><<<spmm_grid, 256, 0, stream>>>(B1, B2, B4, norm, row_off, csr_src, perm, N_NODES);
    spmm_bf16<false><<<spmm_grid, 256, 0, stream>>>(B4, B3, nullptr, norm, row_off, csr_src, perm, N_NODES);
    // layer 2: GEMM -> hF (B0 as fp32, 64 cols)
    gemm_mfma<4, false><<<gemm_grid, 256, 0, stream>>>(B5, B2, B3, Wp2, b2, nullptr, nullptr, nullptr, (float*)B0, N_NODES);
    // readout
    maxpool2<<<(N_NODES + 255) / 256, 256, 0, stream>>>((const float*)B0, gid, (unsigned int*)out, N_NODES);
}

// Round 6
// 380.022 us; speedup vs baseline: 1.6900x; 1.6900x over previous
//
#include <hip/hip_runtime.h>
#include <hip/hip_bf16.h>

#define N_NODES 50000
#define N_EDGES 600000
#define N_GRAPHS 100
#define M_PAD 50176  // 392 * 128

typedef __bf16 bf16_t;
typedef __attribute__((ext_vector_type(8))) __bf16 bf16x8;
typedef __attribute__((ext_vector_type(2))) __bf16 bf16x2;
typedef __attribute__((ext_vector_type(4))) float f32x4;

// ---------------- degree / norm ----------------
__global__ void degk(const int* __restrict__ dst, int* __restrict__ deg, int n) {
    int i = blockIdx.x * 256 + threadIdx.x;
    if (i < n) atomicAdd(&deg[dst[i]], 1);
}

__global__ void normk(const int* __restrict__ deg, float* __restrict__ norm, int n) {
    int i = blockIdx.x * 256 + threadIdx.x;
    if (i < n) {
        float d = fmaxf((float)deg[i], 1.0f);
        norm[i] = 1.0f / sqrtf(d);
    }
}

// ---------------- hierarchical exclusive scan (row offsets) ----------------
__global__ __launch_bounds__(1024) void scan1(const int* __restrict__ deg,
                                              int* __restrict__ row_off,
                                              int* __restrict__ partial, int n) {
    __shared__ int buf[1024];
    int i = blockIdx.x * 1024 + threadIdx.x;
    int v = (i < n) ? deg[i] : 0;
    buf[threadIdx.x] = v;
    __syncthreads();
    for (int off = 1; off < 1024; off <<= 1) {
        int t = (threadIdx.x >= off) ? buf[threadIdx.x - off] : 0;
        __syncthreads();
        buf[threadIdx.x] += t;
        __syncthreads();
    }
    if (i < n) row_off[i + 1] = buf[threadIdx.x];
    if (threadIdx.x == 1023) partial[blockIdx.x] = buf[1023];
}

__global__ void scan2(int* __restrict__ partial, int nchunks) {
    int lane = threadIdx.x;
    int v = (lane < nchunks) ? partial[lane] : 0;
    for (int off = 1; off < 64; off <<= 1) {
        int t = __shfl_up(v, off, 64);
        if (lane >= off) v += t;
    }
    int ex = __shfl_up(v, 1, 64);
    if (lane == 0) ex = 0;
    if (lane < nchunks) partial[lane] = ex;
}

__global__ void scan3(int* __restrict__ row_off, const int* __restrict__ partial, int n) {
    int i = blockIdx.x * 256 + threadIdx.x;
    if (i == 0) row_off[0] = 0;
    if (i < n) row_off[i + 1] += partial[i >> 10];
}

// ---------------- CSR scatter ----------------
__global__ void scatterk(const int* __restrict__ src, const int* __restrict__ dst,
                         const int* __restrict__ row_off, int* __restrict__ cursor,
                         int* __restrict__ csr_src, int n) {
    int e = blockIdx.x * 256 + threadIdx.x;
    if (e >= n) return;
    int d = dst[e];
    int pos = atomicAdd(&cursor[d], 1);
    csr_src[row_off[d] + pos] = src[e];
}

// ---------------- prescale: xb = bf16(x), xs = bf16(x*norm) ----------------
__global__ void prescale(const float* __restrict__ x, const float* __restrict__ norm,
                         bf16_t* __restrict__ xb, bf16_t* __restrict__ xs, int n) {
    int i = blockIdx.x * 256 + threadIdx.x;
    if (i >= n * 64) return;
    int node = i >> 6;
    int c = (i & 63) * 2;
    float2 v = *(const float2*)(x + (size_t)node * 128 + c);
    float nd = norm[node];
    bf16x2 vb; vb[0] = (bf16_t)v.x; vb[1] = (bf16_t)v.y;
    bf16x2 vs; vs[0] = (bf16_t)(v.x * nd); vs[1] = (bf16_t)(v.y * nd);
    *(bf16x2*)(xb + (size_t)node * 128 + c) = vb;
    *(bf16x2*)(xs + (size_t)node * 128 + c) = vs;
}

// ---------------- W permute to MFMA B-fragment layout + bf16 ----------------
__global__ void permW(const float* __restrict__ W, bf16_t* __restrict__ Wp, int K, int N) {
    int i = blockIdx.x * 256 + threadIdx.x;
    if (i >= K * N) return;
    int k = i / N, n = i - k * N;
    int kt = k >> 5, q = (k >> 3) & 3, j = k & 7;
    int nt = n >> 4, ln = n & 15;
    int lane = q * 16 + ln;
    Wp[(((size_t)kt * (N >> 4) + nt) * 64 + lane) * 8 + j] = (bf16_t)W[i];
}

// ---------------- column-blocked SpMM, XCD-pinned colgroups ----------------
// 4 colgroups of 32 feats. cg = blockIdx&3; consecutive blocks round-robin
// over 8 XCDs and 8 % 4 == 0, so XCD k always runs cg k%4 -> per-XCD gather
// working set = 50000*64B = 3.2MB < 4MB L2 (vs 12.8MB unsliced). Indices are
// nontemporal-loaded to avoid polluting L2. 4-lane subgroup per node: each
// lane gathers 16B; subgroup covers a contiguous 64B row slice.
template <bool SCALED>
__global__ __launch_bounds__(256) void spmm_cb(const bf16_t* __restrict__ in,
                                               bf16_t* __restrict__ out_c,
                                               bf16_t* __restrict__ out_s,
                                               const float* __restrict__ norm,
                                               const int* __restrict__ row_off,
                                               const int* __restrict__ csr_src, int n) {
    int cg    = blockIdx.x & 3;
    int chunk = blockIdx.x >> 2;
    int sub = threadIdx.x >> 2;   // 64 subgroups of 4 lanes
    int l   = threadIdx.x & 3;    // lane: feats [cg*32 + l*8, +8)
    int node = chunk * 64 + sub;
    if (node >= n) return;
    int col = cg * 32 + l * 8;
    const bf16_t* colp = in + col;
    int e0 = row_off[node], e1 = row_off[node + 1];
    float acc[8] = {};
    int e = e0;
    for (; e + 4 <= e1; e += 4) {
        int s0 = __builtin_nontemporal_load(csr_src + e + 0);
        int s1 = __builtin_nontemporal_load(csr_src + e + 1);
        int s2 = __builtin_nontemporal_load(csr_src + e + 2);
        int s3 = __builtin_nontemporal_load(csr_src + e + 3);
        bf16x8 v0 = *(const bf16x8*)(colp + (size_t)s0 * 128);
        bf16x8 v1 = *(const bf16x8*)(colp + (size_t)s1 * 128);
        bf16x8 v2 = *(const bf16x8*)(colp + (size_t)s2 * 128);
        bf16x8 v3 = *(const bf16x8*)(colp + (size_t)s3 * 128);
#pragma unroll
        for (int j = 0; j < 8; j++)
            acc[j] += ((float)v0[j] + (float)v1[j]) + ((float)v2[j] + (float)v3[j]);
    }
    for (; e < e1; e++) {
        int s = __builtin_nontemporal_load(csr_src + e);
        bf16x8 v = *(const bf16x8*)(colp + (size_t)s * 128);
#pragma unroll
        for (int j = 0; j < 8; j++) acc[j] += (float)v[j];
    }
    float nd = norm[node];
    bf16x8 oc, os;
#pragma unroll
    for (int j = 0; j < 8; j++) {
        float c = acc[j] * nd;
        oc[j] = (bf16_t)c;
        os[j] = (bf16_t)(c * nd);
    }
    *(bf16x8*)(out_c + (size_t)node * 128 + col) = oc;
    if (SCALED) *(bf16x8*)(out_s + (size_t)node * 128 + col) = os;
}

// ---------------- MFMA concat-GEMM: out = relu([f0|f1|f2] @ W + b) ----------------
template <int NT, bool LAYER1>
__global__ __launch_bounds__(256) void gemm_mfma(const bf16_t* __restrict__ f0,
                                                 const bf16_t* __restrict__ f1,
                                                 const bf16_t* __restrict__ f2,
                                                 const bf16_t* __restrict__ Wp,
                                                 const float* __restrict__ bias,
                                                 const float* __restrict__ norm,
                                                 bf16_t* __restrict__ out_b,
                                                 bf16_t* __restrict__ out_s,
                                                 float* __restrict__ out_f, int M) {
    int wave = threadIdx.x >> 6;
    int lane = threadIdx.x & 63;
    int q = lane >> 4, ln = lane & 15;
    int row0 = blockIdx.x * 128 + wave * 32;

    f32x4 acc[2][NT] = {};
    const bf16_t* feats[3] = {f0, f1, f2};
    const bf16x8* Wf = (const bf16x8*)Wp;

#pragma unroll
    for (int kc = 0; kc < 12; kc++) {
        const bf16_t* A = feats[kc >> 2] + (size_t)(kc & 3) * 32 + q * 8;
        bf16x8 a0 = *(const bf16x8*)(A + (size_t)(row0 + ln) * 128);
        bf16x8 a1 = *(const bf16x8*)(A + (size_t)(row0 + 16 + ln) * 128);
        const bf16x8* Bp = Wf + (size_t)kc * NT * 64 + lane;
#pragma unroll
        for (int nt = 0; nt < NT; nt++) {
            bf16x8 b = Bp[nt * 64];
            acc[0][nt] = __builtin_amdgcn_mfma_f32_16x16x32_bf16(a0, b, acc[0][nt], 0, 0, 0);
            acc[1][nt] = __builtin_amdgcn_mfma_f32_16x16x32_bf16(a1, b, acc[1][nt], 0, 0, 0);
        }
    }

    float bv[NT];
#pragma unroll
    for (int nt = 0; nt < NT; nt++) bv[nt] = bias[nt * 16 + ln];

#pragma unroll
    for (int mt = 0; mt < 2; mt++) {
#pragma unroll
        for (int r = 0; r < 4; r++) {
            int row = row0 + mt * 16 + q * 4 + r;
            if (row >= M) continue;
            float nd = LAYER1 ? norm[row] : 0.f;
#pragma unroll
            for (int nt = 0; nt < NT; nt++) {
                int col = nt * 16 + ln;
                float val = fmaxf(acc[mt][nt][r] + bv[nt], 0.f);
                if (LAYER1) {
                    out_b[(size_t)row * 128 + col] = (bf16_t)val;
                    out_s[(size_t)row * 128 + col] = (bf16_t)(val * nd);
                } else {
                    out_f[(size_t)row * 64 + col] = val;
                }
            }
        }
    }
}

// ---------------- parallel per-graph max pool ----------------
__global__ __launch_bounds__(256) void maxpool2(const float* __restrict__ hF,
                                                const int* __restrict__ gid,
                                                unsigned int* __restrict__ out, int n) {
    int wave = threadIdx.x >> 6;
    int lane = threadIdx.x & 63;
    int n0 = blockIdx.x * 256 + wave * 64;
    if (n0 >= n) return;
    int n1 = min(n0 + 64, n);
    int cur = gid[n0];
    float m = 0.f;
    int i = n0;
    for (; i + 4 <= n1; i += 4) {
        int g0 = gid[i + 0], g1 = gid[i + 1], g2 = gid[i + 2], g3 = gid[i + 3];
        float v0 = hF[(size_t)(i + 0) * 64 + lane];
        float v1 = hF[(size_t)(i + 1) * 64 + lane];
        float v2 = hF[(size_t)(i + 2) * 64 + lane];
        float v3 = hF[(size_t)(i + 3) * 64 + lane];
        if (g0 != cur) { atomicMax(&out[cur * 64 + lane], __float_as_uint(m)); cur = g0; m = v0; } else m = fmaxf(m, v0);
        if (g1 != cur) { atomicMax(&out[cur * 64 + lane], __float_as_uint(m)); cur = g1; m = v1; } else m = fmaxf(m, v1);
        if (g2 != cur) { atomicMax(&out[cur * 64 + lane], __float_as_uint(m)); cur = g2; m = v2; } else m = fmaxf(m, v2);
        if (g3 != cur) { atomicMax(&out[cur * 64 + lane], __float_as_uint(m)); cur = g3; m = v3; } else m = fmaxf(m, v3);
    }
    for (; i < n1; i++) {
        int g = gid[i];
        float v = hF[(size_t)i * 64 + lane];
        if (g != cur) { atomicMax(&out[cur * 64 + lane], __float_as_uint(m)); cur = g; m = v; }
        else m = fmaxf(m, v);
    }
    atomicMax(&out[cur * 64 + lane], __float_as_uint(m));
}

extern "C" void kernel_launch(void* const* d_in, const int* in_sizes, int n_in,
                              void* d_out, int out_size, void* d_ws, size_t ws_size,
                              hipStream_t stream) {
    const float* x  = (const float*)d_in[0];
    const float* W1 = (const float*)d_in[1];
    const float* b1 = (const float*)d_in[2];
    const float* W2 = (const float*)d_in[3];
    const float* b2 = (const float*)d_in[4];
    const int* src  = (const int*)d_in[5];
    const int* dst  = (const int*)d_in[6];
    const int* gid  = (const int*)d_in[7];
    float* out = (float*)d_out;

    char* ws = (char*)d_ws;
    size_t off = 0;
    auto take = [&](size_t bytes) {
        void* p = ws + off;
        off = (off + bytes + 255) & ~(size_t)255;
        return p;
    };
    int* deg     = (int*)take((size_t)N_NODES * 4);
    int* cursor  = (int*)take((size_t)N_NODES * 4);
    size_t zero_bytes = off;
    float* norm  = (float*)take((size_t)N_NODES * 4);
    int* row_off = (int*)take((size_t)(N_NODES + 1) * 4);
    int* partial = (int*)take(64 * 4);
    int* csr_src = (int*)take((size_t)N_EDGES * 4);
    bf16_t* Wp1  = (bf16_t*)take((size_t)384 * 128 * 2);
    bf16_t* Wp2  = (bf16_t*)take((size_t)384 * 64 * 2);
    bf16_t* B0 = (bf16_t*)take((size_t)M_PAD * 128 * 2);  // xb      -> hF (fp32 64c)
    bf16_t* B1 = (bf16_t*)take((size_t)M_PAD * 128 * 2);  // xs      -> hL1s
    bf16_t* B2 = (bf16_t*)take((size_t)M_PAD * 128 * 2);  // c1b     -> d1b
    bf16_t* B3 = (bf16_t*)take((size_t)M_PAD * 128 * 2);  // c2b     -> d2b
    bf16_t* B4 = (bf16_t*)take((size_t)M_PAD * 128 * 2);  // u1b     -> u2b
    bf16_t* B5 = (bf16_t*)take((size_t)M_PAD * 128 * 2);  // hL1b
    (void)ws_size; (void)in_sizes; (void)n_in; (void)out_size;

    hipMemsetAsync(d_ws, 0, zero_bytes, stream);
    hipMemsetAsync(d_out, 0, (size_t)N_GRAPHS * 64 * 4, stream);

    degk<<<(N_EDGES + 255) / 256, 256, 0, stream>>>(dst, deg, N_EDGES);
    normk<<<(N_NODES + 255) / 256, 256, 0, stream>>>(deg, norm, N_NODES);

    int nchunks = (N_NODES + 1023) / 1024;
    scan1<<<nchunks, 1024, 0, stream>>>(deg, row_off, partial, N_NODES);
    scan2<<<1, 64, 0, stream>>>(partial, nchunks);
    scan3<<<(N_NODES + 255) / 256, 256, 0, stream>>>(row_off, partial, N_NODES);
    scatterk<<<(N_EDGES + 255) / 256, 256, 0, stream>>>(src, dst, row_off, cursor, csr_src, N_EDGES);

    prescale<<<(N_NODES * 64 + 255) / 256, 256, 0, stream>>>(x, norm, B0, B1, N_NODES);
    permW<<<(384 * 128 + 255) / 256, 256, 0, stream>>>(W1, Wp1, 384, 128);
    permW<<<(384 * 64 + 255) / 256, 256, 0, stream>>>(W2, Wp2, 384, 64);

    int spmm_grid = ((N_NODES + 63) / 64) * 4;  // 782 node-chunks x 4 colgroups
    int gemm_grid = M_PAD / 128;                // 392
    // layer 1: hops
    spmm_cb<true><<<spmm_grid, 256, 0, stream>>>(B1, B2, B4, norm, row_off, csr_src, N_NODES);
    spmm_cb<false><<<spmm_grid, 256, 0, stream>>>(B4, B3, nullptr, norm, row_off, csr_src, N_NODES);
    // layer 1: GEMM -> hL1b (B5), hL1s (B1)
    gemm_mfma<8, true><<<gemm_grid, 256, 0, stream>>>(B0, B2, B3, Wp1, b1, norm, B5, B1, nullptr, N_NODES);
    // layer 2: hops
    spmm_cb<true><<<spmm_grid, 256, 0, stream>>>(B1, B2, B4, norm, row_off, csr_src, N_NODES);
    spmm_cb<false><<<spmm_grid, 256, 0, stream>>>(B4, B3, nullptr, norm, row_off, csr_src, N_NODES);
    // layer 2: GEMM -> hF (B0 as fp32, 64 cols)
    gemm_mfma<4, false><<<gemm_grid, 256, 0, stream>>>(B5, B2, B3, Wp2, b2, nullptr, nullptr, nullptr, (float*)B0, N_NODES);
    // readout
    maxpool2<<<(N_NODES + 255) / 256, 256, 0, stream>>>((const float*)B0, gid, (unsigned int*)out, N_NODES);
}

// Round 7
// 349.320 us; speedup vs baseline: 1.8386x; 1.0879x over previous
//
#include <hip/hip_runtime.h>
#include <hip/hip_bf16.h>

#define N_NODES 50000
#define N_EDGES 600000
#define N_GRAPHS 100
#define M_PAD 50176  // 392 * 128

typedef __bf16 bf16_t;
typedef __attribute__((ext_vector_type(8))) __bf16 bf16x8;
typedef __attribute__((ext_vector_type(2))) __bf16 bf16x2;
typedef __attribute__((ext_vector_type(4))) float f32x4;

// ---------------- degree / norm ----------------
__global__ void degk(const int* __restrict__ dst, int* __restrict__ deg, int n) {
    int i = blockIdx.x * 256 + threadIdx.x;
    if (i < n) atomicAdd(&deg[dst[i]], 1);
}

__global__ void normk(const int* __restrict__ deg, float* __restrict__ norm, int n) {
    int i = blockIdx.x * 256 + threadIdx.x;
    if (i < n) {
        float d = fmaxf((float)deg[i], 1.0f);
        norm[i] = 1.0f / sqrtf(d);
    }
}

// ---------------- hierarchical exclusive scan (row offsets) ----------------
__global__ __launch_bounds__(1024) void scan1(const int* __restrict__ deg,
                                              int* __restrict__ row_off,
                                              int* __restrict__ partial, int n) {
    __shared__ int buf[1024];
    int i = blockIdx.x * 1024 + threadIdx.x;
    int v = (i < n) ? deg[i] : 0;
    buf[threadIdx.x] = v;
    __syncthreads();
    for (int off = 1; off < 1024; off <<= 1) {
        int t = (threadIdx.x >= off) ? buf[threadIdx.x - off] : 0;
        __syncthreads();
        buf[threadIdx.x] += t;
        __syncthreads();
    }
    if (i < n) row_off[i + 1] = buf[threadIdx.x];
    if (threadIdx.x == 1023) partial[blockIdx.x] = buf[1023];
}

__global__ void scan2(int* __restrict__ partial, int nchunks) {
    int lane = threadIdx.x;
    int v = (lane < nchunks) ? partial[lane] : 0;
    for (int off = 1; off < 64; off <<= 1) {
        int t = __shfl_up(v, off, 64);
        if (lane >= off) v += t;
    }
    int ex = __shfl_up(v, 1, 64);
    if (lane == 0) ex = 0;
    if (lane < nchunks) partial[lane] = ex;
}

__global__ void scan3(int* __restrict__ row_off, const int* __restrict__ partial, int n) {
    int i = blockIdx.x * 256 + threadIdx.x;
    if (i == 0) row_off[0] = 0;
    if (i < n) row_off[i + 1] += partial[i >> 10];
}

// ---------------- CSR scatter ----------------
__global__ void scatterk(const int* __restrict__ src, const int* __restrict__ dst,
                         const int* __restrict__ row_off, int* __restrict__ cursor,
                         int* __restrict__ csr_src, int n) {
    int e = blockIdx.x * 256 + threadIdx.x;
    if (e >= n) return;
    int d = dst[e];
    int pos = atomicAdd(&cursor[d], 1);
    csr_src[row_off[d] + pos] = src[e];
}

// ---------------- prescale: xb = bf16(x) ----------------
__global__ void prescale(const float* __restrict__ x, bf16_t* __restrict__ xb, int n) {
    int i = blockIdx.x * 256 + threadIdx.x;
    if (i >= n * 64) return;
    int node = i >> 6;
    int c = (i & 63) * 2;
    float2 v = *(const float2*)(x + (size_t)node * 128 + c);
    bf16x2 vb; vb[0] = (bf16_t)v.x; vb[1] = (bf16_t)v.y;
    *(bf16x2*)(xb + (size_t)node * 128 + c) = vb;
}

// ---------------- W permute to MFMA B-fragment layout + bf16 ----------------
__global__ void permW(const float* __restrict__ W, bf16_t* __restrict__ Wp, int K, int N) {
    int i = blockIdx.x * 256 + threadIdx.x;
    if (i >= K * N) return;
    int k = i / N, n = i - k * N;
    int kt = k >> 5, q = (k >> 3) & 3, j = k & 7;
    int nt = n >> 4, ln = n & 15;
    int lane = q * 16 + ln;
    Wp[(((size_t)kt * (N >> 4) + nt) * 64 + lane) * 8 + j] = (bf16_t)W[i];
}

// ---------------- SpMM, 64-col (one full 128B line) groups, XCD-pinned ----------------
// out[d] = norm[d] * sum_s norm[s] * in[s]. cg = blockIdx&1 selects cols
// [cg*64, cg*64+64) = exactly one cache line per row -> no half-line waste.
// Round-robin block->XCD (blk%8): even XCDs own cg0, odd own cg1 ->
// per-XCD gather WS = 50000*128B = 6.4MB. norm[s] folded in via fma
// (norm array is 200KB, L2-resident), so no scaled feature copies exist.
// 8-lane subgroup per node, 16B per lane; unroll x8 -> x4 -> scalar.
__global__ __launch_bounds__(256) void spmm2(const bf16_t* __restrict__ in,
                                             bf16_t* __restrict__ out,
                                             const float* __restrict__ norm,
                                             const int* __restrict__ row_off,
                                             const int* __restrict__ csr_src, int n) {
    int cg    = blockIdx.x & 1;
    int chunk = blockIdx.x >> 1;
    int sub = threadIdx.x >> 3;   // 32 subgroups of 8 lanes
    int l   = threadIdx.x & 7;    // cols [cg*64 + l*8, +8)
    int node = chunk * 32 + sub;
    if (node >= n) return;
    int col = cg * 64 + l * 8;
    const bf16_t* colp = in + col;
    int e0 = row_off[node], e1 = row_off[node + 1];
    float acc[8] = {};
    int e = e0;
    for (; e + 8 <= e1; e += 8) {
        int s[8];
#pragma unroll
        for (int u = 0; u < 8; u++) s[u] = __builtin_nontemporal_load(csr_src + e + u);
        bf16x8 v[8];
#pragma unroll
        for (int u = 0; u < 8; u++) v[u] = *(const bf16x8*)(colp + (size_t)s[u] * 128);
        float ns[8];
#pragma unroll
        for (int u = 0; u < 8; u++) ns[u] = norm[s[u]];
#pragma unroll
        for (int u = 0; u < 8; u++)
#pragma unroll
            for (int j = 0; j < 8; j++) acc[j] += ns[u] * (float)v[u][j];
    }
    for (; e + 4 <= e1; e += 4) {
        int s[4];
#pragma unroll
        for (int u = 0; u < 4; u++) s[u] = __builtin_nontemporal_load(csr_src + e + u);
        bf16x8 v[4];
#pragma unroll
        for (int u = 0; u < 4; u++) v[u] = *(const bf16x8*)(colp + (size_t)s[u] * 128);
        float ns[4];
#pragma unroll
        for (int u = 0; u < 4; u++) ns[u] = norm[s[u]];
#pragma unroll
        for (int u = 0; u < 4; u++)
#pragma unroll
            for (int j = 0; j < 8; j++) acc[j] += ns[u] * (float)v[u][j];
    }
    for (; e < e1; e++) {
        int s = __builtin_nontemporal_load(csr_src + e);
        float ns = norm[s];
        bf16x8 v = *(const bf16x8*)(colp + (size_t)s * 128);
#pragma unroll
        for (int j = 0; j < 8; j++) acc[j] += ns * (float)v[j];
    }
    float nd = norm[node];
    bf16x8 o;
#pragma unroll
    for (int j = 0; j < 8; j++) o[j] = (bf16_t)(acc[j] * nd);
    *(bf16x8*)(out + (size_t)node * 128 + col) = o;
}

// ---------------- MFMA concat-GEMM: out = relu([f0|f1|f2] @ W + b) ----------------
// BF16OUT: bf16 output, stride 128 (layer1). else fp32 output, stride 64 (layer2).
template <int NT, bool BF16OUT>
__global__ __launch_bounds__(256) void gemm_mfma(const bf16_t* __restrict__ f0,
                                                 const bf16_t* __restrict__ f1,
                                                 const bf16_t* __restrict__ f2,
                                                 const bf16_t* __restrict__ Wp,
                                                 const float* __restrict__ bias,
                                                 bf16_t* __restrict__ out_b,
                                                 float* __restrict__ out_f, int M) {
    int wave = threadIdx.x >> 6;
    int lane = threadIdx.x & 63;
    int q = lane >> 4, ln = lane & 15;
    int row0 = blockIdx.x * 128 + wave * 32;

    f32x4 acc[2][NT] = {};
    const bf16_t* feats[3] = {f0, f1, f2};
    const bf16x8* Wf = (const bf16x8*)Wp;

#pragma unroll
    for (int kc = 0; kc < 12; kc++) {
        const bf16_t* A = feats[kc >> 2] + (size_t)(kc & 3) * 32 + q * 8;
        bf16x8 a0 = *(const bf16x8*)(A + (size_t)(row0 + ln) * 128);
        bf16x8 a1 = *(const bf16x8*)(A + (size_t)(row0 + 16 + ln) * 128);
        const bf16x8* Bp = Wf + (size_t)kc * NT * 64 + lane;
#pragma unroll
        for (int nt = 0; nt < NT; nt++) {
            bf16x8 b = Bp[nt * 64];
            acc[0][nt] = __builtin_amdgcn_mfma_f32_16x16x32_bf16(a0, b, acc[0][nt], 0, 0, 0);
            acc[1][nt] = __builtin_amdgcn_mfma_f32_16x16x32_bf16(a1, b, acc[1][nt], 0, 0, 0);
        }
    }

    float bv[NT];
#pragma unroll
    for (int nt = 0; nt < NT; nt++) bv[nt] = bias[nt * 16 + ln];

#pragma unroll
    for (int mt = 0; mt < 2; mt++) {
#pragma unroll
        for (int r = 0; r < 4; r++) {
            int row = row0 + mt * 16 + q * 4 + r;
            if (row >= M) continue;
#pragma unroll
            for (int nt = 0; nt < NT; nt++) {
                int col = nt * 16 + ln;
                float val = fmaxf(acc[mt][nt][r] + bv[nt], 0.f);
                if (BF16OUT) out_b[(size_t)row * 128 + col] = (bf16_t)val;
                else         out_f[(size_t)row * 64 + col] = val;
            }
        }
    }
}

// ---------------- parallel per-graph max pool ----------------
__global__ __launch_bounds__(256) void maxpool2(const float* __restrict__ hF,
                                                const int* __restrict__ gid,
                                                unsigned int* __restrict__ out, int n) {
    int wave = threadIdx.x >> 6;
    int lane = threadIdx.x & 63;
    int n0 = blockIdx.x * 256 + wave * 64;
    if (n0 >= n) return;
    int n1 = min(n0 + 64, n);
    int cur = gid[n0];
    float m = 0.f;
    int i = n0;
    for (; i + 4 <= n1; i += 4) {
        int g0 = gid[i + 0], g1 = gid[i + 1], g2 = gid[i + 2], g3 = gid[i + 3];
        float v0 = hF[(size_t)(i + 0) * 64 + lane];
        float v1 = hF[(size_t)(i + 1) * 64 + lane];
        float v2 = hF[(size_t)(i + 2) * 64 + lane];
        float v3 = hF[(size_t)(i + 3) * 64 + lane];
        if (g0 != cur) { atomicMax(&out[cur * 64 + lane], __float_as_uint(m)); cur = g0; m = v0; } else m = fmaxf(m, v0);
        if (g1 != cur) { atomicMax(&out[cur * 64 + lane], __float_as_uint(m)); cur = g1; m = v1; } else m = fmaxf(m, v1);
        if (g2 != cur) { atomicMax(&out[cur * 64 + lane], __float_as_uint(m)); cur = g2; m = v2; } else m = fmaxf(m, v2);
        if (g3 != cur) { atomicMax(&out[cur * 64 + lane], __float_as_uint(m)); cur = g3; m = v3; } else m = fmaxf(m, v3);
    }
    for (; i < n1; i++) {
        int g = gid[i];
        float v = hF[(size_t)i * 64 + lane];
        if (g != cur) { atomicMax(&out[cur * 64 + lane], __float_as_uint(m)); cur = g; m = v; }
        else m = fmaxf(m, v);
    }
    atomicMax(&out[cur * 64 + lane], __float_as_uint(m));
}

extern "C" void kernel_launch(void* const* d_in, const int* in_sizes, int n_in,
                              void* d_out, int out_size, void* d_ws, size_t ws_size,
                              hipStream_t stream) {
    const float* x  = (const float*)d_in[0];
    const float* W1 = (const float*)d_in[1];
    const float* b1 = (const float*)d_in[2];
    const float* W2 = (const float*)d_in[3];
    const float* b2 = (const float*)d_in[4];
    const int* src  = (const int*)d_in[5];
    const int* dst  = (const int*)d_in[6];
    const int* gid  = (const int*)d_in[7];
    float* out = (float*)d_out;

    char* ws = (char*)d_ws;
    size_t off = 0;
    auto take = [&](size_t bytes) {
        void* p = ws + off;
        off = (off + bytes + 255) & ~(size_t)255;
        return p;
    };
    int* deg     = (int*)take((size_t)N_NODES * 4);
    int* cursor  = (int*)take((size_t)N_NODES * 4);
    size_t zero_bytes = off;
    float* norm  = (float*)take((size_t)N_NODES * 4);
    int* row_off = (int*)take((size_t)(N_NODES + 1) * 4);
    int* partial = (int*)take(64 * 4);
    int* csr_src = (int*)take((size_t)N_EDGES * 4);
    bf16_t* Wp1  = (bf16_t*)take((size_t)384 * 128 * 2);
    bf16_t* Wp2  = (bf16_t*)take((size_t)384 * 64 * 2);
    bf16_t* B0 = (bf16_t*)take((size_t)M_PAD * 128 * 2);  // xb
    bf16_t* B1 = (bf16_t*)take((size_t)M_PAD * 128 * 2);  // hF (fp32, 64 cols)
    bf16_t* B2 = (bf16_t*)take((size_t)M_PAD * 128 * 2);  // c1b  -> d1b
    bf16_t* B3 = (bf16_t*)take((size_t)M_PAD * 128 * 2);  // c2b  -> d2b
    bf16_t* B5 = (bf16_t*)take((size_t)M_PAD * 128 * 2);  // hL1b
    (void)ws_size; (void)in_sizes; (void)n_in; (void)out_size;

    hipMemsetAsync(d_ws, 0, zero_bytes, stream);
    hipMemsetAsync(d_out, 0, (size_t)N_GRAPHS * 64 * 4, stream);

    degk<<<(N_EDGES + 255) / 256, 256, 0, stream>>>(dst, deg, N_EDGES);
    normk<<<(N_NODES + 255) / 256, 256, 0, stream>>>(deg, norm, N_NODES);

    int nchunks = (N_NODES + 1023) / 1024;
    scan1<<<nchunks, 1024, 0, stream>>>(deg, row_off, partial, N_NODES);
    scan2<<<1, 64, 0, stream>>>(partial, nchunks);
    scan3<<<(N_NODES + 255) / 256, 256, 0, stream>>>(row_off, partial, N_NODES);
    scatterk<<<(N_EDGES + 255) / 256, 256, 0, stream>>>(src, dst, row_off, cursor, csr_src, N_EDGES);

    prescale<<<(N_NODES * 64 + 255) / 256, 256, 0, stream>>>(x, B0, N_NODES);
    permW<<<(384 * 128 + 255) / 256, 256, 0, stream>>>(W1, Wp1, 384, 128);
    permW<<<(384 * 64 + 255) / 256, 256, 0, stream>>>(W2, Wp2, 384, 64);

    int spmm_grid = ((N_NODES + 31) / 32) * 2;  // node-chunks x 2 colgroups
    int gemm_grid = M_PAD / 128;                // 392
    // layer 1: hops (norm folded into gather)
    spmm2<<<spmm_grid, 256, 0, stream>>>(B0, B2, norm, row_off, csr_src, N_NODES);
    spmm2<<<spmm_grid, 256, 0, stream>>>(B2, B3, norm, row_off, csr_src, N_NODES);
    // layer 1: GEMM -> hL1b (B5)
    gemm_mfma<8, true><<<gemm_grid, 256, 0, stream>>>(B0, B2, B3, Wp1, b1, B5, nullptr, N_NODES);
    // layer 2: hops
    spmm2<<<spmm_grid, 256, 0, stream>>>(B5, B2, norm, row_off, csr_src, N_NODES);
    spmm2<<<spmm_grid, 256, 0, stream>>>(B2, B3, norm, row_off, csr_src, N_NODES);
    // layer 2: GEMM -> hF (B1 as fp32, 64 cols)
    gemm_mfma<4, false><<<gemm_grid, 256, 0, stream>>>(B5, B2, B3, Wp2, b2, nullptr, (float*)B1, N_NODES);
    // readout
    maxpool2<<<(N_NODES + 255) / 256, 256, 0, stream>>>((const float*)B1, gid, (unsigned int*)out, N_NODES);
}

// Round 8
// 314.410 us; speedup vs baseline: 2.0427x; 1.1110x over previous
//
#include <hip/hip_runtime.h>
#include <hip/hip_bf16.h>

#define N_NODES 50000
#define N_EDGES 600000
#define N_GRAPHS 100
#define M_PAD 50176  // 392 * 128

typedef __bf16 bf16_t;
typedef __attribute__((ext_vector_type(8))) __bf16 bf16x8;
typedef __attribute__((ext_vector_type(2))) __bf16 bf16x2;
typedef __attribute__((ext_vector_type(4))) float f32x4;

// ---------------- degree ----------------
__global__ void degk(const int* __restrict__ dst, int* __restrict__ deg, int n) {
    int i = blockIdx.x * 256 + threadIdx.x;
    if (i < n) atomicAdd(&deg[dst[i]], 1);
}

// ---------------- scan1 + norm fused ----------------
__global__ __launch_bounds__(1024) void scan1(const int* __restrict__ deg,
                                              int* __restrict__ row_off,
                                              int* __restrict__ partial,
                                              float* __restrict__ norm, int n) {
    __shared__ int buf[1024];
    int i = blockIdx.x * 1024 + threadIdx.x;
    int v = (i < n) ? deg[i] : 0;
    if (i < n) norm[i] = rsqrtf(fmaxf((float)v, 1.0f));
    buf[threadIdx.x] = v;
    __syncthreads();
    for (int off = 1; off < 1024; off <<= 1) {
        int t = (threadIdx.x >= off) ? buf[threadIdx.x - off] : 0;
        __syncthreads();
        buf[threadIdx.x] += t;
        __syncthreads();
    }
    if (i < n) row_off[i + 1] = buf[threadIdx.x];
    if (threadIdx.x == 1023) partial[blockIdx.x] = buf[1023];
}

__global__ void scan2(int* __restrict__ partial, int nchunks) {
    int lane = threadIdx.x;
    int v = (lane < nchunks) ? partial[lane] : 0;
    for (int off = 1; off < 64; off <<= 1) {
        int t = __shfl_up(v, off, 64);
        if (lane >= off) v += t;
    }
    int ex = __shfl_up(v, 1, 64);
    if (lane == 0) ex = 0;
    if (lane < nchunks) partial[lane] = ex;
}

__global__ void scan3(int* __restrict__ row_off, const int* __restrict__ partial, int n) {
    int i = blockIdx.x * 256 + threadIdx.x;
    if (i == 0) row_off[0] = 0;
    if (i < n) row_off[i + 1] += partial[i >> 10];
}

// ---------------- CSR scatter ----------------
__global__ void scatterk(const int* __restrict__ src, const int* __restrict__ dst,
                         const int* __restrict__ row_off, int* __restrict__ cursor,
                         int* __restrict__ csr_src, int n) {
    int e = blockIdx.x * 256 + threadIdx.x;
    if (e >= n) return;
    int d = dst[e];
    int pos = atomicAdd(&cursor[d], 1);
    csr_src[row_off[d] + pos] = src[e];
}

// ---------------- prescale: xb = bf16(x) ----------------
__global__ void prescale(const float* __restrict__ x, bf16_t* __restrict__ xb, int n) {
    int i = blockIdx.x * 256 + threadIdx.x;
    if (i >= n * 64) return;
    int node = i >> 6;
    int c = (i & 63) * 2;
    float2 v = *(const float2*)(x + (size_t)node * 128 + c);
    bf16x2 vb; vb[0] = (bf16_t)v.x; vb[1] = (bf16_t)v.y;
    *(bf16x2*)(xb + (size_t)node * 128 + c) = vb;
}

// ---------------- W1+W2 permute to MFMA B-fragment layout, single dispatch ----------------
__global__ void permWall(const float* __restrict__ W1, const float* __restrict__ W2,
                         bf16_t* __restrict__ Wp1, bf16_t* __restrict__ Wp2) {
    int i = blockIdx.x * 256 + threadIdx.x;
    const float* W; bf16_t* Wp; int N;
    if (i < 384 * 128) { W = W1; Wp = Wp1; N = 128; }
    else if (i < 384 * 128 + 384 * 64) { i -= 384 * 128; W = W2; Wp = Wp2; N = 64; }
    else return;
    int k = i / N, n = i - k * N;
    int kt = k >> 5, q = (k >> 3) & 3, j = k & 7;
    int nt = n >> 4, ln = n & 15;
    int lane = q * 16 + ln;
    Wp[(((size_t)kt * (N >> 4) + nt) * 64 + lane) * 8 + j] = (bf16_t)W[i];
}

// ---------------- SpMM: out[d] = norm[d] * sum_s norm[s]*in[s] ----------------
// r4-proven structure: 16-lane subgroup covers the full 256B row in one wave
// instr (4 rows/instr/wave); single pass over the L2-resident index list
// (regular loads — nontemporal evicted it across the 4 passes); norm folded
// via fma (200KB, L2-hit broadcast). Unroll x8 to keep ~64 lines in flight
// per wave (latency/MSHR-bound regime).
__global__ __launch_bounds__(256) void spmm3(const bf16_t* __restrict__ in,
                                             bf16_t* __restrict__ out,
                                             const float* __restrict__ norm,
                                             const int* __restrict__ row_off,
                                             const int* __restrict__ csr_src, int n) {
    int sub = threadIdx.x >> 4;   // 16 subgroups of 16 lanes
    int l   = threadIdx.x & 15;   // cols [l*8, l*8+8)
    int node = blockIdx.x * 16 + sub;
    if (node >= n) return;
    const bf16_t* colp = in + l * 8;
    int e0 = row_off[node], e1 = row_off[node + 1];
    float acc[8] = {};
    int e = e0;
    for (; e + 8 <= e1; e += 8) {
        int s[8];
#pragma unroll
        for (int u = 0; u < 8; u++) s[u] = csr_src[e + u];
        bf16x8 v[8];
#pragma unroll
        for (int u = 0; u < 8; u++) v[u] = *(const bf16x8*)(colp + (size_t)s[u] * 128);
        float ns[8];
#pragma unroll
        for (int u = 0; u < 8; u++) ns[u] = norm[s[u]];
#pragma unroll
        for (int u = 0; u < 8; u++)
#pragma unroll
            for (int j = 0; j < 8; j++) acc[j] += ns[u] * (float)v[u][j];
    }
    for (; e + 4 <= e1; e += 4) {
        int s[4];
#pragma unroll
        for (int u = 0; u < 4; u++) s[u] = csr_src[e + u];
        bf16x8 v[4];
#pragma unroll
        for (int u = 0; u < 4; u++) v[u] = *(const bf16x8*)(colp + (size_t)s[u] * 128);
        float ns[4];
#pragma unroll
        for (int u = 0; u < 4; u++) ns[u] = norm[s[u]];
#pragma unroll
        for (int u = 0; u < 4; u++)
#pragma unroll
            for (int j = 0; j < 8; j++) acc[j] += ns[u] * (float)v[u][j];
    }
    for (; e < e1; e++) {
        int s = csr_src[e];
        float ns = norm[s];
        bf16x8 v = *(const bf16x8*)(colp + (size_t)s * 128);
#pragma unroll
        for (int j = 0; j < 8; j++) acc[j] += ns * (float)v[j];
    }
    float nd = norm[node];
    bf16x8 o;
#pragma unroll
    for (int j = 0; j < 8; j++) o[j] = (bf16_t)(acc[j] * nd);
    *(bf16x8*)(out + (size_t)node * 128 + l * 8) = o;
}

// ---------------- MFMA concat-GEMM: out = relu([f0|f1|f2] @ W + b) ----------------
template <int NT, bool BF16OUT>
__global__ __launch_bounds__(256) void gemm_mfma(const bf16_t* __restrict__ f0,
                                                 const bf16_t* __restrict__ f1,
                                                 const bf16_t* __restrict__ f2,
                                                 const bf16_t* __restrict__ Wp,
                                                 const float* __restrict__ bias,
                                                 bf16_t* __restrict__ out_b,
                                                 float* __restrict__ out_f, int M) {
    int wave = threadIdx.x >> 6;
    int lane = threadIdx.x & 63;
    int q = lane >> 4, ln = lane & 15;
    int row0 = blockIdx.x * 128 + wave * 32;

    f32x4 acc[2][NT] = {};
    const bf16_t* feats[3] = {f0, f1, f2};
    const bf16x8* Wf = (const bf16x8*)Wp;

#pragma unroll
    for (int kc = 0; kc < 12; kc++) {
        const bf16_t* A = feats[kc >> 2] + (size_t)(kc & 3) * 32 + q * 8;
        bf16x8 a0 = *(const bf16x8*)(A + (size_t)(row0 + ln) * 128);
        bf16x8 a1 = *(const bf16x8*)(A + (size_t)(row0 + 16 + ln) * 128);
        const bf16x8* Bp = Wf + (size_t)kc * NT * 64 + lane;
#pragma unroll
        for (int nt = 0; nt < NT; nt++) {
            bf16x8 b = Bp[nt * 64];
            acc[0][nt] = __builtin_amdgcn_mfma_f32_16x16x32_bf16(a0, b, acc[0][nt], 0, 0, 0);
            acc[1][nt] = __builtin_amdgcn_mfma_f32_16x16x32_bf16(a1, b, acc[1][nt], 0, 0, 0);
        }
    }

    float bv[NT];
#pragma unroll
    for (int nt = 0; nt < NT; nt++) bv[nt] = bias[nt * 16 + ln];

#pragma unroll
    for (int mt = 0; mt < 2; mt++) {
#pragma unroll
        for (int r = 0; r < 4; r++) {
            int row = row0 + mt * 16 + q * 4 + r;
            if (row >= M) continue;
#pragma unroll
            for (int nt = 0; nt < NT; nt++) {
                int col = nt * 16 + ln;
                float val = fmaxf(acc[mt][nt][r] + bv[nt], 0.f);
                if (BF16OUT) out_b[(size_t)row * 128 + col] = (bf16_t)val;
                else         out_f[(size_t)row * 64 + col] = val;
            }
        }
    }
}

// ---------------- parallel per-graph max pool ----------------
__global__ __launch_bounds__(256) void maxpool2(const float* __restrict__ hF,
                                                const int* __restrict__ gid,
                                                unsigned int* __restrict__ out, int n) {
    int wave = threadIdx.x >> 6;
    int lane = threadIdx.x & 63;
    int n0 = blockIdx.x * 256 + wave * 64;
    if (n0 >= n) return;
    int n1 = min(n0 + 64, n);
    int cur = gid[n0];
    float m = 0.f;
    int i = n0;
    for (; i + 4 <= n1; i += 4) {
        int g0 = gid[i + 0], g1 = gid[i + 1], g2 = gid[i + 2], g3 = gid[i + 3];
        float v0 = hF[(size_t)(i + 0) * 64 + lane];
        float v1 = hF[(size_t)(i + 1) * 64 + lane];
        float v2 = hF[(size_t)(i + 2) * 64 + lane];
        float v3 = hF[(size_t)(i + 3) * 64 + lane];
        if (g0 != cur) { atomicMax(&out[cur * 64 + lane], __float_as_uint(m)); cur = g0; m = v0; } else m = fmaxf(m, v0);
        if (g1 != cur) { atomicMax(&out[cur * 64 + lane], __float_as_uint(m)); cur = g1; m = v1; } else m = fmaxf(m, v1);
        if (g2 != cur) { atomicMax(&out[cur * 64 + lane], __float_as_uint(m)); cur = g2; m = v2; } else m = fmaxf(m, v2);
        if (g3 != cur) { atomicMax(&out[cur * 64 + lane], __float_as_uint(m)); cur = g3; m = v3; } else m = fmaxf(m, v3);
    }
    for (; i < n1; i++) {
        int g = gid[i];
        float v = hF[(size_t)i * 64 + lane];
        if (g != cur) { atomicMax(&out[cur * 64 + lane], __float_as_uint(m)); cur = g; m = v; }
        else m = fmaxf(m, v);
    }
    atomicMax(&out[cur * 64 + lane], __float_as_uint(m));
}

extern "C" void kernel_launch(void* const* d_in, const int* in_sizes, int n_in,
                              void* d_out, int out_size, void* d_ws, size_t ws_size,
                              hipStream_t stream) {
    const float* x  = (const float*)d_in[0];
    const float* W1 = (const float*)d_in[1];
    const float* b1 = (const float*)d_in[2];
    const float* W2 = (const float*)d_in[3];
    const float* b2 = (const float*)d_in[4];
    const int* src  = (const int*)d_in[5];
    const int* dst  = (const int*)d_in[6];
    const int* gid  = (const int*)d_in[7];
    float* out = (float*)d_out;

    char* ws = (char*)d_ws;
    size_t off = 0;
    auto take = [&](size_t bytes) {
        void* p = ws + off;
        off = (off + bytes + 255) & ~(size_t)255;
        return p;
    };
    int* deg     = (int*)take((size_t)N_NODES * 4);
    int* cursor  = (int*)take((size_t)N_NODES * 4);
    size_t zero_bytes = off;
    float* norm  = (float*)take((size_t)N_NODES * 4);
    int* row_off = (int*)take((size_t)(N_NODES + 1) * 4);
    int* partial = (int*)take(64 * 4);
    int* csr_src = (int*)take((size_t)N_EDGES * 4);
    bf16_t* Wp1  = (bf16_t*)take((size_t)384 * 128 * 2);
    bf16_t* Wp2  = (bf16_t*)take((size_t)384 * 64 * 2);
    bf16_t* B0 = (bf16_t*)take((size_t)M_PAD * 128 * 2);  // xb
    bf16_t* B1 = (bf16_t*)take((size_t)M_PAD * 128 * 2);  // hF (fp32, 64 cols)
    bf16_t* B2 = (bf16_t*)take((size_t)M_PAD * 128 * 2);  // c1b  -> d1b
    bf16_t* B3 = (bf16_t*)take((size_t)M_PAD * 128 * 2);  // c2b  -> d2b
    bf16_t* B5 = (bf16_t*)take((size_t)M_PAD * 128 * 2);  // hL1b
    (void)ws_size; (void)in_sizes; (void)n_in; (void)out_size;

    hipMemsetAsync(d_ws, 0, zero_bytes, stream);
    hipMemsetAsync(d_out, 0, (size_t)N_GRAPHS * 64 * 4, stream);

    degk<<<(N_EDGES + 255) / 256, 256, 0, stream>>>(dst, deg, N_EDGES);

    int nchunks = (N_NODES + 1023) / 1024;
    scan1<<<nchunks, 1024, 0, stream>>>(deg, row_off, partial, norm, N_NODES);
    scan2<<<1, 64, 0, stream>>>(partial, nchunks);
    scan3<<<(N_NODES + 255) / 256, 256, 0, stream>>>(row_off, partial, N_NODES);
    scatterk<<<(N_EDGES + 255) / 256, 256, 0, stream>>>(src, dst, row_off, cursor, csr_src, N_EDGES);

    prescale<<<(N_NODES * 64 + 255) / 256, 256, 0, stream>>>(x, B0, N_NODES);
    permWall<<<(384 * 192 + 255) / 256, 256, 0, stream>>>(W1, W2, Wp1, Wp2);

    int spmm_grid = (N_NODES + 15) / 16;  // 16 nodes/block
    int gemm_grid = M_PAD / 128;          // 392
    // layer 1: hops (norm folded into gather)
    spmm3<<<spmm_grid, 256, 0, stream>>>(B0, B2, norm, row_off, csr_src, N_NODES);
    spmm3<<<spmm_grid, 256, 0, stream>>>(B2, B3, norm, row_off, csr_src, N_NODES);
    // layer 1: GEMM -> hL1b (B5)
    gemm_mfma<8, true><<<gemm_grid, 256, 0, stream>>>(B0, B2, B3, Wp1, b1, B5, nullptr, N_NODES);
    // layer 2: hops
    spmm3<<<spmm_grid, 256, 0, stream>>>(B5, B2, norm, row_off, csr_src, N_NODES);
    spmm3<<<spmm_grid, 256, 0, stream>>>(B2, B3, norm, row_off, csr_src, N_NODES);
    // layer 2: GEMM -> hF (B1 as fp32, 64 cols)
    gemm_mfma<4, false><<<gemm_grid, 256, 0, stream>>>(B5, B2, B3, Wp2, b2, nullptr, (float*)B1, N_NODES);
    // readout
    maxpool2<<<(N_NODES + 255) / 256, 256, 0, stream>>>((const float*)B1, gid, (unsigned int*)out, N_NODES);
}